// Round 20
// baseline (42.172 us; speedup 1.0000x reference)
//
#include <hip/hip_runtime.h>
#include <stdint.h>

// Shapes fixed by setup_inputs: B=4, D=20, H=W=128, HW=16384, 1024 tiles of 64 voxels.
// R20 = R19 (merged finalize, atomic-RMW poll) at launch_bounds(512,6):
//  - R19 failed ONLY on register budget: (512,8)'s 64-VGPR cap + merged tail
//    -> allocator collapse to VGPR=32 -> scratch spill -> 41us. (512,6) caps
//    at 85 (carried R15's 17.7us); body ~60 + tail ~15 fits, no spill.
//  - poll uses device-scope atomicAdd(ctr,0) reads (R18 lesson: plain volatile
//    loads see stale per-XCD L2 lines; atomics round-trip the coherence point).
//  - 16 counters spaced 64B apart (blockIdx&15 -> 64 signals each, no pileup).
//  - block 0 wave 0 spins, __threadfence-acquires, reduces 1024 records,
//    writes out[0]. All other blocks retire independently (deadlock-safe).
#define HW     16384
#define NTILES 1024
#define NCTR   16
#define INFI   0x7f800000

__global__ __launch_bounds__(512, 6) void chamfer_all(
    const float* __restrict__ pred,   // [B, 60, HW]  channel c*20+i
    const float* __restrict__ gt,     // [B, 60, HW]  channel j*3+c
    const float* __restrict__ cmask,  // [B, 20, HW]
    const float* __restrict__ vmask,  // [B, HW]
    const float* __restrict__ pnum,   // [B, HW]
    const float* __restrict__ gnum,   // [B, HW]
    float* __restrict__ ws,
    float* __restrict__ out)
{
    __shared__ int rm_m[20][64];   // per-row selected min (float bits)
    __shared__ int cd_s[20][64];   // per-col min (d2s)
    __shared__ int mx_s[64];       // per-voxel max dist
    __shared__ int bt_s[64];       // per-voxel cmask bits

    const int tid  = threadIdx.x;
    const int lane = tid & 63;     // voxel within tile
    const int w    = tid >> 6;     // wave 0..7
    const int ri   = w >> 2;       // 0..1 -> rows i0..i0+9
    const int cj   = w & 3;        // 0..3 -> cols j0..j0+4
    const int i0   = ri * 10, j0 = cj * 5;
    const int k    = blockIdx.x * 64 + lane;
    const int b    = k >> 14;
    const int hw   = k & (HW - 1);
    const size_t pb = (size_t)b * 60 * HW + hw;
    const size_t cb = (size_t)b * 20 * HW + hw;

    // ---- independent coalesced loads up-front (256B per wave-instr)
    float dxv[5], dyv[5], dzv[5], cmf[5];
    #pragma unroll
    for (int jj = 0; jj < 5; ++jj) {
        dxv[jj] = gt[pb + (size_t)(3 * (j0 + jj)    ) * HW];
        dyv[jj] = gt[pb + (size_t)(3 * (j0 + jj) + 1) * HW];
        dzv[jj] = gt[pb + (size_t)(3 * (j0 + jj) + 2) * HW];
        cmf[jj] = cmask[cb + (size_t)(j0 + jj) * HW];
    }
    float vw = 0.f, pn = 0.f, gn = 0.f;
    if (w == 0) { vw = vmask[k]; pn = pnum[k]; gn = gnum[k]; }

    // ---- init LDS while loads are in flight
    {
        int* pm = &rm_m[0][0]; int* pc = &cd_s[0][0];
        #pragma unroll
        for (int q = 0; q < 3; ++q) {
            const int t = tid + q * 512;
            if (t < 1280) { pm[t] = INFI; pc[t] = INFI; }
        }
        if (tid < 64) { mx_s[tid] = 0; bt_s[tid] = 0; }
    }
    __syncthreads();

    // ---- publish cmask bits BEFORE the hot loop (ri==0 waves cover all cols)
    unsigned mybits = 0u;
    #pragma unroll
    for (int jj = 0; jj < 5; ++jj)
        if (cmf[jj] > 0.f) mybits |= 1u << jj;
    if (ri == 0 && mybits) atomicOr(&bt_s[lane], (int)(mybits << j0));
    __syncthreads();

    const unsigned cmbits = (unsigned)bt_s[lane];
    // selected cols for the s2d row-min: masked cols if any masked globally,
    // else all cols (their min + maxd is exact via vals[1])
    const unsigned sel = cmbits ? mybits : 0x1Fu;

    const float INF = __int_as_float(INFI);
    float rmm[10], cds[5], mx = 0.f;
    #pragma unroll
    for (int t = 0; t < 10; ++t) rmm[t] = INF;
    #pragma unroll
    for (int t = 0; t < 5; ++t) cds[t] = INF;

    #pragma unroll
    for (int r = 0; r < 10; ++r) {
        const int i = i0 + r;
        const float sx = pred[pb + (size_t)(i)      * HW];
        const float sy = pred[pb + (size_t)(20 + i) * HW];
        const float sz = pred[pb + (size_t)(40 + i) * HW];
        #pragma unroll
        for (int jj = 0; jj < 5; ++jj) {
            float d = fabsf(sx - dxv[jj]) + fabsf(sy - dyv[jj]) + fabsf(sz - dzv[jj]);
            mx      = fmaxf(mx, d);
            cds[jj] = fminf(cds[jj], d);
            rmm[r]  = fminf(rmm[r], ((sel >> jj) & 1u) ? d : INF);
        }
    }

    // ---- cross-wave combine: int atomics (all values >= 0 -> int order == float order)
    #pragma unroll
    for (int r = 0; r < 10; ++r)
        atomicMin(&rm_m[i0 + r][lane], __float_as_int(rmm[r]));
    #pragma unroll
    for (int jj = 0; jj < 5; ++jj)
        atomicMin(&cd_s[j0 + jj][lane], __float_as_int(cds[jj]));
    atomicMax(&mx_s[lane], __float_as_int(mx));
    __syncthreads();

    // ---- per-tile finalize: wave 0, lane = voxel
    if (w == 0) {
        float srcA = 0.f;
        #pragma unroll
        for (int i = 0; i < 20; ++i) srcA += __int_as_float(rm_m[i][lane]);
        float dsum = 0.f;
        #pragma unroll
        for (int j = 0; j < 20; ++j)
            if ((cmbits >> j) & 1u) dsum += __int_as_float(cd_s[j][lane]);
        const float mxv = __int_as_float(mx_s[lane]);

        float vals[7];
        vals[0] = srcA * vw;                          // src-loss min-sum
        vals[1] = (cmbits == 0u) ? 20.f * vw : 0.f;   // rows needing +max_d
        vals[2] = dsum * vw;                          // dst-loss numerator
        vals[3] = vw * (float)__popc(cmbits);         // dst-loss denominator
        const float diff = pn - gn;
        const float ad = fabsf(diff);
        vals[4] = ((ad < 1.f) ? 0.5f * diff * diff : (ad - 0.5f)) * vw;
        vals[5] = vw;                                 // wsum
        vals[6] = (vw > 0.f) ? mxv : 0.f;             // masked max

        #pragma unroll
        for (int o = 32; o > 0; o >>= 1) {
            #pragma unroll
            for (int x = 0; x < 6; ++x) vals[x] += __shfl_down(vals[x], o);
            vals[6] = fmaxf(vals[6], __shfl_down(vals[6], o));
        }
        if (lane == 0) {
            float* rec = ws + (size_t)blockIdx.x * 8;
            #pragma unroll
            for (int x = 0; x < 7; ++x) rec[x] = vals[x];
            __threadfence();   // release record before signaling
            // 16 counters spaced 64B (16 u32) apart; blockIdx&15 -> 64 each
            atomicAdd((unsigned*)(ws + 8192) + (blockIdx.x & (NCTR - 1)) * 16, 1u);
        }

        // ---- block 0: spin on device-scope atomic reads (per-XCD L2 is not
        // coherent -- plain volatile loads would see stale lines, R18 lesson)
        if (blockIdx.x == 0) {
            unsigned* ctr = (unsigned*)(ws + 8192) + (lane & (NCTR - 1)) * 16;
            const unsigned quota = NTILES / NCTR;   // 64 per counter
            for (;;) {
                unsigned v = (lane < NCTR) ? atomicAdd(ctr, 0u) : quota;
                if (__all(v >= quota)) break;
                __builtin_amdgcn_s_sleep(32);
            }
            __threadfence();   // acquire all records
            float a[6] = {0.f, 0.f, 0.f, 0.f, 0.f, 0.f};
            float fmx = 0.f;
            for (int r = lane; r < NTILES; r += 64) {
                const float* rec = ws + (size_t)r * 8;
                #pragma unroll
                for (int v = 0; v < 6; ++v) a[v] += rec[v];
                fmx = fmaxf(fmx, rec[6]);
            }
            #pragma unroll
            for (int o = 32; o > 0; o >>= 1) {
                #pragma unroll
                for (int v = 0; v < 6; ++v) a[v] += __shfl_down(a[v], o);
                fmx = fmaxf(fmx, __shfl_down(fmx, o));
            }
            if (lane == 0) {
                const float loss_s = (a[0] + a[1] * fmx) / (a[5] * 20.f);
                const float loss_d = a[2] / a[3];
                const float numl   = a[4] / a[5];
                out[0] = loss_s + loss_d + 0.1f * numl;
            }
        }
    }
}

extern "C" void kernel_launch(void* const* d_in, const int* in_sizes, int n_in,
                              void* d_out, int out_size, void* d_ws, size_t ws_size,
                              hipStream_t stream)
{
    const float* pred  = (const float*)d_in[0];
    const float* gt    = (const float*)d_in[1];
    const float* cmask = (const float*)d_in[2];
    const float* vmask = (const float*)d_in[3];
    const float* pnum  = (const float*)d_in[4];
    const float* gnum  = (const float*)d_in[5];
    float* out = (float*)d_out;
    float* ws  = (float*)d_ws;

    // zero the 16 completion counters (1 KB at float-offset 8192)
    hipMemsetAsync(ws + 8192, 0, NCTR * 16 * sizeof(unsigned), stream);
    chamfer_all<<<NTILES, 512, 0, stream>>>(pred, gt, cmask, vmask, pnum, gnum, ws, out);
}

// Round 21
// 17.931 us; speedup vs baseline: 2.3519x; 2.3519x over previous
//
#include <hip/hip_runtime.h>
#include <stdint.h>

// Shapes fixed by setup_inputs: B=4, D=20, H=W=128, HW=16384, 1024 tiles of 64 voxels.
// FINAL (= R15, proven 17.7us): direct-load 8-wave design, branch-free sel.
//  - Block = 64 voxels x 8 waves; wave (ri,cj) owns rows ri*10..+9 x cols cj*5..+4.
//    All loads direct coalesced 256B (independent -> deep MLP, no staging:
//    staged/double-buffered variants R7/R9 were slower).
//  - cmbits published to LDS before the hot loop; sel = cmbits ? mybits : all
//    (exact: min over all j + maxd via vals[1] for the never-taken cmbits==0 case).
//  - Cross-wave combine via LDS int atomicMin/Max (non-negative floats: int
//    order == float order).
//  - Per-block record stores + separate 256-thread fin kernel. Merged-finalize
//    variants (R12/R19/R20) all collapse the register allocator to VGPR=32
//    (spill or rematerialization) -> 41-51us; two-kernel is structurally right.
//  - launch_bounds(512,6): (512,8) caps VGPR at 64 and spills this body (R12).
//  - Session ladder: 42 (naive+contended atomics) -> 22 (uncontended records)
//    -> 18.3 (direct loads) -> 17.7 (this). Contended same-line device atomics
//    were the dominant hidden cost (R2-R6: ~90us tail from 7168 atomics).
#define HW     16384
#define NTILES 1024
#define INFI   0x7f800000

__global__ __launch_bounds__(512, 6) void chamfer_main(
    const float* __restrict__ pred,   // [B, 60, HW]  channel c*20+i
    const float* __restrict__ gt,     // [B, 60, HW]  channel j*3+c
    const float* __restrict__ cmask,  // [B, 20, HW]
    const float* __restrict__ vmask,  // [B, HW]
    const float* __restrict__ pnum,   // [B, HW]
    const float* __restrict__ gnum,   // [B, HW]
    float* __restrict__ ws)
{
    __shared__ int rm_m[20][64];   // per-row selected min (float bits)
    __shared__ int cd_s[20][64];   // per-col min (d2s)
    __shared__ int mx_s[64];       // per-voxel max dist
    __shared__ int bt_s[64];       // per-voxel cmask bits

    const int tid  = threadIdx.x;
    const int lane = tid & 63;     // voxel within tile
    const int w    = tid >> 6;     // wave 0..7
    const int ri   = w >> 2;       // 0..1 -> rows i0..i0+9
    const int cj   = w & 3;        // 0..3 -> cols j0..j0+4
    const int i0   = ri * 10, j0 = cj * 5;
    const int k    = blockIdx.x * 64 + lane;
    const int b    = k >> 14;
    const int hw   = k & (HW - 1);
    const size_t pb = (size_t)b * 60 * HW + hw;
    const size_t cb = (size_t)b * 20 * HW + hw;

    // ---- independent coalesced loads up-front (256B per wave-instr)
    float dxv[5], dyv[5], dzv[5], cmf[5];
    #pragma unroll
    for (int jj = 0; jj < 5; ++jj) {
        dxv[jj] = gt[pb + (size_t)(3 * (j0 + jj)    ) * HW];
        dyv[jj] = gt[pb + (size_t)(3 * (j0 + jj) + 1) * HW];
        dzv[jj] = gt[pb + (size_t)(3 * (j0 + jj) + 2) * HW];
        cmf[jj] = cmask[cb + (size_t)(j0 + jj) * HW];
    }
    float vw = 0.f, pn = 0.f, gn = 0.f;
    if (w == 0) { vw = vmask[k]; pn = pnum[k]; gn = gnum[k]; }

    // ---- init LDS while loads are in flight
    {
        int* pm = &rm_m[0][0]; int* pc = &cd_s[0][0];
        #pragma unroll
        for (int q = 0; q < 3; ++q) {
            const int t = tid + q * 512;
            if (t < 1280) { pm[t] = INFI; pc[t] = INFI; }
        }
        if (tid < 64) { mx_s[tid] = 0; bt_s[tid] = 0; }
    }
    __syncthreads();

    // ---- publish cmask bits BEFORE the hot loop (ri==0 waves cover all cols)
    unsigned mybits = 0u;
    #pragma unroll
    for (int jj = 0; jj < 5; ++jj)
        if (cmf[jj] > 0.f) mybits |= 1u << jj;
    if (ri == 0 && mybits) atomicOr(&bt_s[lane], (int)(mybits << j0));
    __syncthreads();

    const unsigned cmbits = (unsigned)bt_s[lane];
    // selected cols for the s2d row-min: masked cols if any masked globally,
    // else all cols (their min + maxd is exact via vals[1])
    const unsigned sel = cmbits ? mybits : 0x1Fu;

    const float INF = __int_as_float(INFI);
    float rmm[10], cds[5], mx = 0.f;
    #pragma unroll
    for (int t = 0; t < 10; ++t) rmm[t] = INF;
    #pragma unroll
    for (int t = 0; t < 5; ++t) cds[t] = INF;

    #pragma unroll
    for (int r = 0; r < 10; ++r) {
        const int i = i0 + r;
        const float sx = pred[pb + (size_t)(i)      * HW];
        const float sy = pred[pb + (size_t)(20 + i) * HW];
        const float sz = pred[pb + (size_t)(40 + i) * HW];
        #pragma unroll
        for (int jj = 0; jj < 5; ++jj) {
            float d = fabsf(sx - dxv[jj]) + fabsf(sy - dyv[jj]) + fabsf(sz - dzv[jj]);
            mx      = fmaxf(mx, d);
            cds[jj] = fminf(cds[jj], d);
            rmm[r]  = fminf(rmm[r], ((sel >> jj) & 1u) ? d : INF);
        }
    }

    // ---- cross-wave combine: int atomics (all values >= 0 -> int order == float order)
    #pragma unroll
    for (int r = 0; r < 10; ++r)
        atomicMin(&rm_m[i0 + r][lane], __float_as_int(rmm[r]));
    #pragma unroll
    for (int jj = 0; jj < 5; ++jj)
        atomicMin(&cd_s[j0 + jj][lane], __float_as_int(cds[jj]));
    atomicMax(&mx_s[lane], __float_as_int(mx));
    __syncthreads();

    // ---- per-tile finalize: wave 0, lane = voxel
    if (w == 0) {
        float srcA = 0.f;
        #pragma unroll
        for (int i = 0; i < 20; ++i) srcA += __int_as_float(rm_m[i][lane]);
        float dsum = 0.f;
        #pragma unroll
        for (int j = 0; j < 20; ++j)
            if ((cmbits >> j) & 1u) dsum += __int_as_float(cd_s[j][lane]);
        const float mxv = __int_as_float(mx_s[lane]);

        float vals[7];
        vals[0] = srcA * vw;                          // src-loss min-sum
        vals[1] = (cmbits == 0u) ? 20.f * vw : 0.f;   // rows needing +max_d
        vals[2] = dsum * vw;                          // dst-loss numerator
        vals[3] = vw * (float)__popc(cmbits);         // dst-loss denominator
        const float diff = pn - gn;
        const float ad = fabsf(diff);
        vals[4] = ((ad < 1.f) ? 0.5f * diff * diff : (ad - 0.5f)) * vw;
        vals[5] = vw;                                 // wsum
        vals[6] = (vw > 0.f) ? mxv : 0.f;             // masked max

        #pragma unroll
        for (int o = 32; o > 0; o >>= 1) {
            #pragma unroll
            for (int x = 0; x < 6; ++x) vals[x] += __shfl_down(vals[x], o);
            vals[6] = fmaxf(vals[6], __shfl_down(vals[6], o));
        }
        if (lane == 0) {
            float* rec = ws + (size_t)blockIdx.x * 8;
            #pragma unroll
            for (int x = 0; x < 7; ++x) rec[x] = vals[x];
        }
    }
}

__global__ __launch_bounds__(256) void chamfer_fin(
    const float* __restrict__ ws, float* __restrict__ out)
{
    __shared__ float red[4][8];
    const int tid  = threadIdx.x;
    const int lane = tid & 63;
    const int wv   = tid >> 6;
    float a[6] = {0.f, 0.f, 0.f, 0.f, 0.f, 0.f};
    float mx = 0.f;
    for (int r = tid; r < NTILES; r += 256) {
        const float* rec = ws + (size_t)r * 8;
        #pragma unroll
        for (int v = 0; v < 6; ++v) a[v] += rec[v];
        mx = fmaxf(mx, rec[6]);
    }
    #pragma unroll
    for (int o = 32; o > 0; o >>= 1) {
        #pragma unroll
        for (int v = 0; v < 6; ++v) a[v] += __shfl_down(a[v], o);
        mx = fmaxf(mx, __shfl_down(mx, o));
    }
    if (lane == 0) {
        #pragma unroll
        for (int v = 0; v < 6; ++v) red[wv][v] = a[v];
        red[wv][6] = mx;
    }
    __syncthreads();
    if (tid == 0) {
        #pragma unroll
        for (int v = 0; v < 6; ++v) a[v] = red[0][v] + red[1][v] + red[2][v] + red[3][v];
        mx = fmaxf(fmaxf(red[0][6], red[1][6]), fmaxf(red[2][6], red[3][6]));
        const float loss_s = (a[0] + a[1] * mx) / (a[5] * 20.f);
        const float loss_d = a[2] / a[3];
        const float numl   = a[4] / a[5];
        out[0] = loss_s + loss_d + 0.1f * numl;
    }
}

extern "C" void kernel_launch(void* const* d_in, const int* in_sizes, int n_in,
                              void* d_out, int out_size, void* d_ws, size_t ws_size,
                              hipStream_t stream)
{
    const float* pred  = (const float*)d_in[0];
    const float* gt    = (const float*)d_in[1];
    const float* cmask = (const float*)d_in[2];
    const float* vmask = (const float*)d_in[3];
    const float* pnum  = (const float*)d_in[4];
    const float* gnum  = (const float*)d_in[5];
    float* out = (float*)d_out;
    float* ws  = (float*)d_ws;

    chamfer_main<<<NTILES, 512, 0, stream>>>(pred, gt, cmask, vmask, pnum, gnum, ws);
    chamfer_fin<<<1, 256, 0, stream>>>(ws, out);
}